// Round 5
// baseline (107.246 us; speedup 1.0000x reference)
//
#include <hip/hip_runtime.h>
#include <hip/hip_cooperative_groups.h>

namespace cg = cooperative_groups;

#define H_ 224
#define W_ 224
#define NIMG 48
#define NBINS 33          // bins 0..31 real; bin 32 = beyond t_max (ignored)
#define JOBS_PER_IMG 112  // 28 row-groups (8 rows) x 4 col-groups (63 cols)
#define WPB 4             // waves per block
#define NBLK (NIMG * JOBS_PER_IMG / WPB)   // 1344
#define BLKS_PER_IMG (JOBS_PER_IMG / WPB)  // 28

// smallest k in [0,32] with k * fl(1/31) >= x  (== searchsorted(linspace(0,1,32), x, 'left'))
__device__ __forceinline__ int bin_of(float x) {
    const float C = 1.0f / 31.0f;
    int k = (int)__builtin_ceilf(x * 31.0f);
    k = min(k, 32);
    if ((float)(k - 1) * C >= x) --k;          // k==0: (-1)*C >= x>=0 is false, safe
    else if ((float)k * C < x) ++k;
    return k;
}

__device__ __forceinline__ void hist_phase(const float* __restrict__ x,
                                           int* __restrict__ gh) {
    __shared__ int hist[WPB][NBINS];
    const int tid = threadIdx.x;
    const int wave = tid >> 6;
    const int lane = tid & 63;

    if (lane < NBINS) hist[wave][lane] = 0;    // wave-private init, no barrier needed

    const int job  = blockIdx.x * WPB + wave;
    const int img  = job / JOBS_PER_IMG;
    const int jj   = job % JOBS_PER_IMG;
    const int rowg = jj >> 2;
    const int colg = jj & 3;
    const int col  = colg * 63 + lane;          // 1-col halo overlap between groups
    const bool produce = (lane < 63) && (col < W_);
    const bool hasR    = produce && (col < W_ - 1);
    const int  colc    = min(col, W_ - 1);      // clamp inactive lanes' loads

    const float* base = x + (size_t)img * (H_ * W_) + (size_t)(rowg * 8) * W_ + colc;
    int* hw = hist[wave];

    int bcur = bin_of(base[0]);
    const int r0 = rowg * 8;

#pragma unroll
    for (int ri = 0; ri < 8; ++ri) {
        const bool hasD = (r0 + ri < H_ - 1);   // wave-uniform
        int bnext = hasD ? bin_of(base[(ri + 1) * W_]) : 0;
        int sh = __shfl_down(bcur | (bnext << 16), 1, 64);
        int bR = sh & 0xffff, bDR = sh >> 16;
        if (hasD) {
            int e1 = max(bcur, bR);
            int e2 = max(bcur, bnext);
            if (hasR) {
                int lo = min(e1, e2), hi = max(e1, e2);
                int sq = max(hi, bDR);
                if (bcur != lo) { atomicAdd(&hw[bcur], 1); atomicAdd(&hw[lo], -1); }
                if (sq != hi)   { atomicAdd(&hw[sq], 1);   atomicAdd(&hw[hi], -1); }
            } else if (produce) {               // col 223: pixel + v-edge only
                if (bcur != e2) { atomicAdd(&hw[bcur], 1); atomicAdd(&hw[e2], -1); }
            }
        } else {                                // row 223: pixel + h-edge only
            int e1 = max(bcur, bR);
            if (hasR) {
                if (bcur != e1) { atomicAdd(&hw[bcur], 1); atomicAdd(&hw[e1], -1); }
            } else if (produce) {               // bottom-right corner
                atomicAdd(&hw[bcur], 1);
            }
        }
        bcur = bnext;
    }
    __syncthreads();

    if (tid < NBINS) {
        gh[blockIdx.x * NBINS + tid] =
            hist[0][tid] + hist[1][tid] + hist[2][tid] + hist[3][tid];
    }
}

__device__ __forceinline__ void final_phase(const int* __restrict__ gh,
                                            float* __restrict__ out, int img) {
    const int lane = threadIdx.x;
    if (lane < 32) {
        int v = 0;
        const int* base = gh + img * BLKS_PER_IMG * NBINS + lane;
#pragma unroll
        for (int s = 0; s < BLKS_PER_IMG; ++s) v += base[s * NBINS];
        for (int off = 1; off < 32; off <<= 1) {
            int n = __shfl_up(v, off, 64);
            if (lane >= off) v += n;
        }
        out[img * 32 + lane] = (float)v;
    }
}

__global__ __launch_bounds__(256) void ecc_coop(const float* __restrict__ x,
                                                int* __restrict__ gh,
                                                float* __restrict__ out) {
    hist_phase(x, gh);
    cg::this_grid().sync();
    if (blockIdx.x < NIMG) final_phase(gh, out, blockIdx.x);
}

// fallback path (two nodes), in case cooperative launch is rejected
__global__ __launch_bounds__(256) void ecc_hist(const float* __restrict__ x,
                                                int* __restrict__ gh) {
    hist_phase(x, gh);
}
__global__ __launch_bounds__(64) void ecc_final(const int* __restrict__ gh,
                                                float* __restrict__ out) {
    final_phase(gh, out, blockIdx.x);
}

extern "C" void kernel_launch(void* const* d_in, const int* in_sizes, int n_in,
                              void* d_out, int out_size, void* d_ws, size_t ws_size,
                              hipStream_t stream) {
    const float* x = (const float*)d_in[0];
    float* out = (float*)d_out;
    int* gh = (int*)d_ws;

    void* args[] = {(void*)&x, (void*)&gh, (void*)&out};
    hipError_t err = hipLaunchCooperativeKernel((const void*)ecc_coop,
                                                dim3(NBLK), dim3(256),
                                                args, 0, stream);
    if (err != hipSuccess) {
        ecc_hist<<<NBLK, 256, 0, stream>>>(x, gh);
        ecc_final<<<NIMG, 64, 0, stream>>>(gh, out);
    }
}

// Round 6
// 42.764 us; speedup vs baseline: 2.5079x; 2.5079x over previous
//
#include <hip/hip_runtime.h>

#define H_ 224
#define W_ 224
#define NIMG 48
#define NBINS 33          // bins 0..31 real; bin 32 = beyond t_max (ignored)
#define JOBS_PER_IMG 112  // 28 row-groups (8 rows) x 4 col-groups (63 cols)
#define WPB 4             // waves per block
#define NBLK (NIMG * JOBS_PER_IMG / WPB)   // 1344
#define BLKS_PER_IMG (JOBS_PER_IMG / WPB)  // 28
#define MAGIC 0x5ECCD0DE

// smallest k in [0,32] with k * fl(1/31) >= x  (== searchsorted(linspace(0,1,32), x, 'left'))
__device__ __forceinline__ int bin_of(float x) {
    const float C = 1.0f / 31.0f;
    int k = (int)__builtin_ceilf(x * 31.0f);
    k = min(k, 32);
    if ((float)(k - 1) * C >= x) --k;          // k==0: (-1)*C >= x>=0 is false, safe
    else if ((float)k * C < x) ++k;
    return k;
}

__global__ __launch_bounds__(256) void ecc_onepass(const float* __restrict__ x,
                                                   int* __restrict__ gh,
                                                   int* __restrict__ flags,
                                                   float* __restrict__ out) {
    __shared__ int hist[WPB][NBINS];
    const int tid = threadIdx.x;
    const int wave = tid >> 6;
    const int lane = tid & 63;

    if (lane < NBINS) hist[wave][lane] = 0;    // wave-private init, no barrier needed

    const int blk  = blockIdx.x;
    const int job  = blk * WPB + wave;
    const int img  = job / JOBS_PER_IMG;
    const int jj   = job % JOBS_PER_IMG;
    const int rowg = jj >> 2;
    const int colg = jj & 3;
    const int col  = colg * 63 + lane;          // 1-col halo overlap between groups
    const bool produce = (lane < 63) && (col < W_);
    const bool hasR    = produce && (col < W_ - 1);
    const int  colc    = min(col, W_ - 1);      // clamp inactive lanes' loads

    const float* base = x + (size_t)img * (H_ * W_) + (size_t)(rowg * 8) * W_ + colc;
    int* hw = hist[wave];

    int bcur = bin_of(base[0]);
    const int r0 = rowg * 8;

#pragma unroll
    for (int ri = 0; ri < 8; ++ri) {
        const bool hasD = (r0 + ri < H_ - 1);   // wave-uniform
        int bnext = hasD ? bin_of(base[(ri + 1) * W_]) : 0;
        int sh = __shfl_down(bcur | (bnext << 16), 1, 64);
        int bR = sh & 0xffff, bDR = sh >> 16;
        if (hasD) {
            int e1 = max(bcur, bR);
            int e2 = max(bcur, bnext);
            if (hasR) {
                int lo = min(e1, e2), hi = max(e1, e2);
                int sq = max(hi, bDR);
                if (bcur != lo) { atomicAdd(&hw[bcur], 1); atomicAdd(&hw[lo], -1); }
                if (sq != hi)   { atomicAdd(&hw[sq], 1);   atomicAdd(&hw[hi], -1); }
            } else if (produce) {               // col 223: pixel + v-edge only
                if (bcur != e2) { atomicAdd(&hw[bcur], 1); atomicAdd(&hw[e2], -1); }
            }
        } else {                                // row 223: pixel + h-edge only
            int e1 = max(bcur, bR);
            if (hasR) {
                if (bcur != e1) { atomicAdd(&hw[bcur], 1); atomicAdd(&hw[e1], -1); }
            } else if (produce) {               // bottom-right corner
                atomicAdd(&hw[bcur], 1);
            }
        }
        bcur = bnext;
    }
    __syncthreads();

    if (tid < NBINS) {
        gh[blk * NBINS + tid] =
            hist[0][tid] + hist[1][tid] + hist[2][tid] + hist[3][tid];
    }
    __syncthreads();

    if (tid == 0) {
        __threadfence();  // make gh stores visible device-wide before flag
        __hip_atomic_store(&flags[blk], MAGIC, __ATOMIC_RELEASE,
                           __HIP_MEMORY_SCOPE_AGENT);
    }

    // blocks 0..47: reduce + scan + store for image blk
    if (blk < NIMG) {
        if (tid < BLKS_PER_IMG) {
            while (__hip_atomic_load(&flags[blk * BLKS_PER_IMG + tid],
                                     __ATOMIC_ACQUIRE,
                                     __HIP_MEMORY_SCOPE_AGENT) != MAGIC) {
            }
        }
        __syncthreads();
        if (tid < 32) {
            int v = 0;
            const int* basep = gh + blk * BLKS_PER_IMG * NBINS + tid;
#pragma unroll
            for (int s = 0; s < BLKS_PER_IMG; ++s) v += basep[s * NBINS];
            for (int off = 1; off < 32; off <<= 1) {
                int n = __shfl_up(v, off, 64);
                if (tid >= off) v += n;
            }
            out[blk * 32 + tid] = (float)v;
        }
    }
}

extern "C" void kernel_launch(void* const* d_in, const int* in_sizes, int n_in,
                              void* d_out, int out_size, void* d_ws, size_t ws_size,
                              hipStream_t stream) {
    const float* x = (const float*)d_in[0];
    float* out = (float*)d_out;
    int* gh = (int*)d_ws;                 // NBLK*NBINS ints
    int* flags = gh + NBLK * NBINS;       // NBLK ints

    ecc_onepass<<<NBLK, 256, 0, stream>>>(x, gh, flags, out);
}

// Round 7
// 12.522 us; speedup vs baseline: 8.5644x; 3.4150x over previous
//
#include <hip/hip_runtime.h>

#define H_ 224
#define W_ 224
#define NIMG 48
#define NBINS 33          // bins 0..31 real; bin 32 = beyond t_max (ignored)
#define ROWS_PER 14       // rows per wave-job
#define ROWG 16           // 224/14 row-groups
#define JOBS_PER_IMG (ROWG * 4)            // 64: 16 row-groups x 4 col-groups (63 cols)
#define WPB 4             // waves per block
#define NBLK (NIMG * JOBS_PER_IMG / WPB)   // 768
#define BLKS_PER_IMG (JOBS_PER_IMG / WPB)  // 16

// smallest k in [0,32] with k * fl(1/31) >= x  (== searchsorted(linspace(0,1,32), x, 'left'))
__device__ __forceinline__ int bin_of(float x) {
    const float C = 1.0f / 31.0f;
    int k = (int)__builtin_ceilf(x * 31.0f);
    k = min(k, 32);
    if ((float)(k - 1) * C >= x) --k;          // k==0: (-1)*C >= x>=0 is false, safe
    else if ((float)k * C < x) ++k;
    return k;
}

__global__ __launch_bounds__(256) void ecc_hist(const float* __restrict__ x,
                                                int* __restrict__ gh) {
    __shared__ int hist[WPB][NBINS];
    const int tid = threadIdx.x;
    const int wave = tid >> 6;
    const int lane = tid & 63;

    if (lane < NBINS) hist[wave][lane] = 0;    // wave-private init, no barrier needed

    const int blk  = blockIdx.x;
    const int job  = blk * WPB + wave;
    const int img  = job / JOBS_PER_IMG;
    const int jj   = job % JOBS_PER_IMG;
    const int rowg = jj >> 2;                  // 0..15
    const int colg = jj & 3;                   // 0..3
    const int col  = colg * 63 + lane;         // 1-col halo overlap between groups
    const bool produce = (lane < 63) && (col < W_);
    const bool hasR    = produce && (col < W_ - 1);
    const int  colc    = min(col, W_ - 1);     // clamp inactive lanes' loads
    const int  r0      = rowg * ROWS_PER;
    const int  maxoff  = (rowg == ROWG - 1) ? (ROWS_PER - 1) : ROWS_PER;  // last valid row offset

    const float* base = x + (size_t)img * (H_ * W_) + (size_t)r0 * W_ + colc;
    int* hw = hist[wave];

    // software pipeline: f_nx holds row r0+ri+1's value when iteration ri computes
    float f_cur = base[0];
    float f_nx  = base[min(1, maxoff) * W_];
    int bcur = bin_of(f_cur);

#pragma unroll
    for (int ri = 0; ri < ROWS_PER; ++ri) {
        // issue load of row r0+ri+2 early (clamped; redundant load if past end)
        float f_nx2 = base[min(ri + 2, maxoff) * W_];
        const bool hasD = (ri + 1 <= maxoff);  // wave-uniform
        int bnext = hasD ? bin_of(f_nx) : 0;
        int sh = __shfl_down(bcur | (bnext << 16), 1, 64);
        int bR = sh & 0xffff, bDR = sh >> 16;
        if (hasD) {
            int e1 = max(bcur, bR);
            int e2 = max(bcur, bnext);
            if (hasR) {
                int lo = min(e1, e2), hi = max(e1, e2);
                int sq = max(hi, bDR);
                if (bcur != lo) { atomicAdd(&hw[bcur], 1); atomicAdd(&hw[lo], -1); }
                if (sq != hi)   { atomicAdd(&hw[sq], 1);   atomicAdd(&hw[hi], -1); }
            } else if (produce) {               // col 223: pixel + v-edge only
                if (bcur != e2) { atomicAdd(&hw[bcur], 1); atomicAdd(&hw[e2], -1); }
            }
        } else {                                // row 223: pixel + h-edge only
            int e1 = max(bcur, bR);
            if (hasR) {
                if (bcur != e1) { atomicAdd(&hw[bcur], 1); atomicAdd(&hw[e1], -1); }
            } else if (produce) {               // bottom-right corner
                atomicAdd(&hw[bcur], 1);
            }
        }
        bcur = bnext;
        f_nx = f_nx2;
    }
    __syncthreads();

    if (tid < NBINS) {
        gh[blk * NBINS + tid] =
            hist[0][tid] + hist[1][tid] + hist[2][tid] + hist[3][tid];
    }
}

__global__ __launch_bounds__(64) void ecc_final(const int* __restrict__ gh,
                                                float* __restrict__ out) {
    const int img = blockIdx.x;
    const int lane = threadIdx.x;
    if (lane < 32) {
        int v = 0;
        const int* base = gh + img * BLKS_PER_IMG * NBINS + lane;
#pragma unroll
        for (int s = 0; s < BLKS_PER_IMG; ++s) v += base[s * NBINS];
        for (int off = 1; off < 32; off <<= 1) {
            int n = __shfl_up(v, off, 64);
            if (lane >= off) v += n;
        }
        out[img * 32 + lane] = (float)v;
    }
}

extern "C" void kernel_launch(void* const* d_in, const int* in_sizes, int n_in,
                              void* d_out, int out_size, void* d_ws, size_t ws_size,
                              hipStream_t stream) {
    const float* x = (const float*)d_in[0];
    float* out = (float*)d_out;
    int* gh = (int*)d_ws;

    ecc_hist<<<NBLK, 256, 0, stream>>>(x, gh);
    ecc_final<<<NIMG, 64, 0, stream>>>(gh, out);
}